// Round 14
// baseline (626.179 us; speedup 1.0000x reference)
//
#include <hip/hip_runtime.h>

typedef __attribute__((ext_vector_type(8))) __bf16 bf16x8;
typedef __attribute__((ext_vector_type(4))) float f32x4;
typedef _Float16 hf2 __attribute__((ext_vector_type(2)));
typedef _Float16 hf8 __attribute__((ext_vector_type(8)));
typedef unsigned short u16;
typedef struct { hf2 v[4]; } hf2x4;   // register-friendly view of hf8

__device__ __forceinline__ float bf2f(u16 h) {
    return __uint_as_float(((unsigned int)h) << 16);
}
__device__ __forceinline__ u16 f2bf(float f) {
    unsigned int u = __float_as_uint(f);
    u += 0x7fffu + ((u >> 16) & 1u);   // RNE
    return (u16)(u >> 16);
}

#if __has_builtin(__builtin_amdgcn_fdot2)
__device__ __forceinline__ float FDOT2(hf2 a, hf2 b, float c) {
    return __builtin_amdgcn_fdot2(a, b, c, false);
}
#else
__device__ __forceinline__ float FDOT2(hf2 a, hf2 b, float c) {
    return c + (float)a[0] + (float)a[1];   // b is all-ones in our use
}
#endif

#define GLOAD_LDS16(gsrc, ldst)                                                          \
    __builtin_amdgcn_global_load_lds(                                                    \
        (__attribute__((address_space(1))) unsigned int*)(gsrc),                         \
        (__attribute__((address_space(3))) unsigned int*)(ldst), 16, 0, 0)

// INSTRUMENTATION ROUND: each launch repeated REPS x (all kernels idempotent)
// so every kernel lands in rocprof's top-5 with full counters. dur_us will be
// ~10x; per-kernel time = instance dur. Revert REPS to 1 next round.
static constexpr int REPS = 10;

// ---------------------------------------------------------------------------
// f32 -> bf16/f16 convert with zero-padding. Unused tab entries: blk0=INT_MAX.
// ---------------------------------------------------------------------------
struct CvtDesc { const float* src; u16* dst; int N, K, Npad, Kpad, blk0, fmt; };
struct CvtTab { CvtDesc t[11]; };

__device__ __forceinline__ void do_cvt(const CvtTab& tab, int vb, int tid) {
    int ti = 0;
#pragma unroll
    for (int j = 1; j < 11; ++j)
        if (vb >= tab.t[j].blk0) ti = j;
    const CvtDesc c = tab.t[ti];
    long i = (long)(vb - c.blk0) * 256 + tid;
    long tot = (long)c.Npad * c.Kpad;
    if (i >= tot) return;
    int n = (int)(i / c.Kpad);
    int k = (int)(i - (long)n * c.Kpad);
    float v = (n < c.N && k < c.K) ? c.src[(long)n * c.K + k] : 0.f;
    c.dst[i] = c.fmt ? __builtin_bit_cast(u16, (_Float16)v) : f2bf(v);
}

__global__ __launch_bounds__(256) void cvt_k(CvtTab tab) {
    do_cvt(tab, blockIdx.x, threadIdx.x);
}

// ---------------------------------------------------------------------------
// 128x64-tile double-buffered bf16 MFMA GEMM (2-phase pipeline): STAGE(next)
// issued BEFORE COMPUTE(cur); one vmcnt-drain barrier per K-step.
// 256 thr = 4 waves as 2x2 over (128,64); wave tile 64x32 = acc[4][2].
// XOR-swizzled granules via pre-swizzled global source + linear LDS dest.
// ---------------------------------------------------------------------------
template<int RELU, int HASRES, int RESF16, int MODE>
__device__ __forceinline__ void gemm128_body(
    char* lds,
    const u16* __restrict__ A, int lda,
    const u16* __restrict__ W, int ldw,
    const float* __restrict__ bias,
    u16* __restrict__ outB, int ldo,
    const void* __restrict__ res, int ldr,
    _Float16* __restrict__ outH,
    int nk, int mb, int nb)
{
    const int tid = threadIdx.x;
    const int wave = tid >> 6, lane = tid & 63;
    const int lr = lane & 15, lk = lane >> 4;
    const int wr = wave >> 1, wc = wave & 1;

    f32x4 acc[4][2];
#pragma unroll
    for (int i = 0; i < 4; ++i)
#pragma unroll
        for (int j = 0; j < 2; ++j)
#pragma unroll
            for (int e = 0; e < 4; ++e) acc[i][j][e] = 0.f;

    int ra[4], la[4], rb_[2], lb[2];
#pragma unroll
    for (int t = 0; t < 4; ++t) {
        int g = t * 256 + tid;
        ra[t] = g >> 3; la[t] = (g & 7) ^ (ra[t] & 7);
    }
#pragma unroll
    for (int t = 0; t < 2; ++t) {
        int g = t * 256 + tid;
        rb_[t] = g >> 3; lb[t] = (g & 7) ^ (rb_[t] & 7);
    }

    auto STAGE = [&](int b, int kt) {
        const int kk = kt * 64;
        char* dA = lds + b * 24576;
        char* dB = dA + 16384;
#pragma unroll
        for (int t = 0; t < 4; ++t)
            GLOAD_LDS16(A + (size_t)(mb + ra[t]) * lda + kk + la[t] * 8,
                        dA + t * 4096 + wave * 1024);
#pragma unroll
        for (int t = 0; t < 2; ++t)
            GLOAD_LDS16(W + (size_t)(nb + rb_[t]) * ldw + kk + lb[t] * 8,
                        dB + t * 4096 + wave * 1024);
    };
    auto COMPUTE = [&](int b) {
        char* sA = lds + b * 24576;
        char* sB = sA + 16384;
#pragma unroll
        for (int ks = 0; ks < 2; ++ks) {
            bf16x8 af[4], bfr[2];
#pragma unroll
            for (int mi = 0; mi < 4; ++mi) {
                int m_loc = wr * 64 + mi * 16 + lr;
                int gr = (ks * 4 + lk) ^ (m_loc & 7);
                af[mi] = *(const bf16x8*)(sA + m_loc * 128 + gr * 16);
            }
#pragma unroll
            for (int ni = 0; ni < 2; ++ni) {
                int n_loc = wc * 32 + ni * 16 + lr;
                int gr = (ks * 4 + lk) ^ (n_loc & 7);
                bfr[ni] = *(const bf16x8*)(sB + n_loc * 128 + gr * 16);
            }
#pragma unroll
            for (int mi = 0; mi < 4; ++mi)
#pragma unroll
                for (int ni = 0; ni < 2; ++ni)
                    acc[mi][ni] = __builtin_amdgcn_mfma_f32_16x16x32_bf16(
                        af[mi], bfr[ni], acc[mi][ni], 0, 0, 0);
        }
    };

    STAGE(0, 0);
    __syncthreads();
    int b = 0;
    for (int kt = 0; kt < nk - 1; ++kt) {
        STAGE(b ^ 1, kt + 1);
        COMPUTE(b);
        __syncthreads();
        b ^= 1;
    }
    COMPUTE(b);

    // epilogue: C/D layout col = lane&15, row = (lane>>4)*4 + reg
#pragma unroll
    for (int mi = 0; mi < 4; ++mi) {
#pragma unroll
        for (int ni = 0; ni < 2; ++ni) {
            const int n_g = nb + wc * 32 + ni * 16 + lr;
            const float bv = bias[n_g];
#pragma unroll
            for (int r = 0; r < 4; ++r) {
                const int m_g = mb + wr * 64 + mi * 16 + lk * 4 + r;
                float v = acc[mi][ni][r] + bv;
                if (RELU) v = fmaxf(v, 0.f);
                if (HASRES) {
                    if (RESF16)
                        v += (float)((const _Float16*)res)[(size_t)m_g * ldr + n_g];
                    else
                        v += bf2f(((const u16*)res)[(size_t)m_g * ldr + n_g]);
                }
                if (MODE == 2) outH[(size_t)m_g * 768 + n_g] = (_Float16)v;
                else           outB[(size_t)m_g * ldo + n_g] = f2bf(v);
            }
        }
    }
}

// launch 2: down0 (96 tiles) + adapter (192 tiles: adFH = f16(x@aW.T+ab+x))
//           + cvt of remaining weights/protos — all depend only on launch 1.
__global__ __launch_bounds__(256, 2) void gemm_d0ad_cvt(
    const u16* __restrict__ xb, const u16* __restrict__ Wd0b,
    const float* __restrict__ bd0, u16* __restrict__ h1,
    const u16* __restrict__ aWb, const float* __restrict__ ab,
    _Float16* __restrict__ adFH, CvtTab tabB)
{
    __shared__ __align__(16) char lds[49152];
    const int bid = blockIdx.x;
    if (bid < 96) {
        gemm128_body<1, 0, 0, 0>(lds, xb, 768, Wd0b, 768, bd0, h1, 384,
                                 nullptr, 0, nullptr, 12,
                                 (bid & 15) * 128, (bid >> 4) * 64);
    } else if (bid < 288) {
        const int b2 = bid - 96;
        gemm128_body<0, 1, 0, 2>(lds, xb, 768, aWb, 768, ab, nullptr, 0,
                                 xb, 768, adFH, 12,
                                 (b2 & 15) * 128, (b2 >> 4) * 64);
    } else {
        do_cvt(tabB, bid - 288, threadIdx.x);
    }
}

// ---------------------------------------------------------------------------
// chain512: d1..u2, 128 blocks x 512 thr (8 waves = 4 N-waves x 2 K-waves).
// ---------------------------------------------------------------------------
template<int K, int NPAD, int NREAL, int RES, int OUTG>
__device__ __forceinline__ void layer16s(
    const u16* __restrict__ W, int ldw, const float* __restrict__ bias,
    const u16* actIn, int ldin,
    u16* actOut, int ldout,
    const u16* resid, int ldres,
    u16* __restrict__ gout, int ldg,
    float* comb)
{
    constexpr int TPW = NPAD / 64;
    constexpr int KK = K / 32;
    constexpr int KH = KK / 2;
    const int tid = threadIdx.x;
    const int w = tid >> 6, lane = tid & 63;
    const int nw = w & 3, kw = w >> 2;
    const int lr = lane & 15, lk = lane >> 4;

    f32x4 acc[TPW];
#pragma unroll
    for (int t = 0; t < TPW; ++t)
#pragma unroll
        for (int e = 0; e < 4; ++e) acc[t][e] = 0.f;

#pragma unroll
    for (int s = 0; s < KH; ++s) {
        const int kk = kw * KH + s;
        const bf16x8 a = *(const bf16x8*)&actIn[lr * ldin + kk * 32 + lk * 8];
#pragma unroll
        for (int t = 0; t < TPW; ++t) {
            const int nc = (nw * TPW + t) * 16 + lr;
            const bf16x8 b = *(const bf16x8*)&W[(size_t)nc * ldw + kk * 32 + lk * 8];
            acc[t] = __builtin_amdgcn_mfma_f32_16x16x32_bf16(a, b, acc[t], 0, 0, 0);
        }
    }
    if (kw == 1) {
#pragma unroll
        for (int t = 0; t < TPW; ++t)
            *(f32x4*)(comb + ((size_t)(nw * TPW + t) * 64 + lane) * 4) = acc[t];
    }
    __syncthreads();
    if (kw == 0) {
#pragma unroll
        for (int t = 0; t < TPW; ++t) {
            const f32x4 o = *(const f32x4*)(comb + ((size_t)(nw * TPW + t) * 64 + lane) * 4);
            const int nc = (nw * TPW + t) * 16 + lr;
            const float bv = (nc < NREAL) ? bias[nc] : 0.f;
#pragma unroll
            for (int r = 0; r < 4; ++r) {
                const int row = lk * 4 + r;
                float v = fmaxf(acc[t][r] + o[r] + bv, 0.f);
                if (RES) v += bf2f(resid[row * ldres + nc]);
                const u16 ov = f2bf(v);
                if (OUTG) gout[(size_t)row * ldg + nc] = ov;
                else      actOut[row * ldout + nc] = ov;
            }
        }
    }
    __syncthreads();
}

__global__ __launch_bounds__(512) void chain512(
    const u16* __restrict__ h1,
    const u16* __restrict__ Wd1b, const float* __restrict__ bd1,
    const u16* __restrict__ Wd2b, const float* __restrict__ bd2,
    const u16* __restrict__ Wd3b, const float* __restrict__ bd3,
    const u16* __restrict__ Wu0b, const float* __restrict__ bu0,
    const u16* __restrict__ Wu1b, const float* __restrict__ bu1,
    const u16* __restrict__ Wu2b, const float* __restrict__ bu2,
    u16* __restrict__ u2)
{
    __shared__ u16 As[16 * 392];
    __shared__ u16 Bs[16 * 200];
    __shared__ u16 Cs[16 * 136];
    __shared__ u16 Ds[16 * 72];
    __shared__ float comb[6144];      // 24 tiles x 64 lanes x f32x4 = 24576 B
    const int tid = threadIdx.x;
    const int rb = blockIdx.x * 16;

    for (int i = tid; i < 768; i += 512) {
        const int r = i / 48, c = i - r * 48;
        *(bf16x8*)&As[r * 392 + c * 8] =
            *(const bf16x8*)&h1[(size_t)(rb + r) * 384 + c * 8];
    }
    __syncthreads();
    layer16s<384, 192, 192, 0, 0>(Wd1b, 384, bd1, As, 392, Bs, 200, nullptr, 0, nullptr, 0, comb);
    layer16s<192, 128,  96, 0, 0>(Wd2b, 192, bd2, Bs, 200, Cs, 136, nullptr, 0, nullptr, 0, comb);
    layer16s<128,  64,  48, 0, 0>(Wd3b, 128, bd3, Cs, 136, Ds,  72, nullptr, 0, nullptr, 0, comb);
    u16* E = As;
    u16* F = As + 16 * 136;
    layer16s< 64, 128,  96, 1, 0>(Wu0b,  64, bu0, Ds,  72, E, 136, Cs, 136, nullptr, 0, comb);
    layer16s<128, 192, 192, 1, 0>(Wu1b, 128, bu1, E, 136, F, 200, Bs, 200, nullptr, 0, comb);
    layer16s<192, 384, 384, 0, 1>(Wu2b, 192, bu2, F, 200, nullptr, 0, nullptr, 0,
                                  u2 + (size_t)rb * 384, 384, comb);
}

// launch 4: featH = f16( relu(u2@Wu3.T + bu3) + adFH )   [idempotent]
__global__ __launch_bounds__(256, 2) void gemm_u3(
    const u16* __restrict__ u2, const u16* __restrict__ Wu3b,
    const float* __restrict__ bu3, const _Float16* __restrict__ adFH,
    _Float16* __restrict__ featH)
{
    __shared__ __align__(16) char lds[49152];
    gemm128_body<1, 1, 1, 2>(lds, u2, 384, Wu3b, 384, bu3, nullptr, 0,
                             adFH, 768, featH, 6,
                             blockIdx.x * 128, blockIdx.y * 64);
}

// ---------------------------------------------------------------------------
// L1 head: part[row][z][p] = sum_{d in 96-chunk z} -|feat[row][d]-protos[p][d]|
// Grid (16 rb, 4 pb, 8 z) = 512 blocks (2/CU). Block: 128 rows x 64 p x 96 d.
// ---------------------------------------------------------------------------
__global__ __launch_bounds__(256) void l1_kernel(
    const _Float16* __restrict__ feat, const _Float16* __restrict__ protos,
    float* __restrict__ part)
{
    __shared__ _Float16 fs[128][96];   // 24576 B
    __shared__ hf2 pt[48][64];         // 12288 B  [d-pair][proto]
    const int tid = threadIdx.x;
    const int tp = tid & 15, tr = tid >> 4;
    const int rb = blockIdx.x * 128;
    const int pb = blockIdx.y * 64;
    const int db = blockIdx.z * 96;

    for (int i = tid; i < 1536; i += 256) {
        const int r = i / 12, c = i - r * 12;
        *(hf8*)&fs[r][c * 8] =
            *(const hf8*)&feat[(size_t)(rb + r) * 768 + db + c * 8];
    }
    {
        const int sp = tid & 63, q = tid >> 6;
#pragma unroll
        for (int t = 0; t < 3; ++t) {
            const hf8 v = *(const hf8*)&protos[(size_t)(pb + sp) * 768 + db + q * 24 + t * 8];
            const hf2x4 w = __builtin_bit_cast(hf2x4, v);
            const int p0 = q * 12 + t * 4;
#pragma unroll
            for (int e = 0; e < 4; ++e)
                pt[p0 + e][sp] = w.v[e];
        }
    }
    __syncthreads();

    float acc[8][4];
#pragma unroll
    for (int i = 0; i < 8; ++i)
#pragma unroll
        for (int j = 0; j < 4; ++j) acc[i][j] = 0.f;

    const hf2 one2 = {(_Float16)1.0f, (_Float16)1.0f};
#pragma unroll 2
    for (int g = 0; g < 12; ++g) {
        hf2x4 F2[8];
#pragma unroll
        for (int i = 0; i < 8; ++i)
            F2[i] = __builtin_bit_cast(hf2x4, *(const hf8*)&fs[tr + 16 * i][g * 8]);
        hf2x4 P2[4];
#pragma unroll
        for (int q = 0; q < 4; ++q)
            P2[q] = __builtin_bit_cast(hf2x4, *(const hf8*)&pt[g * 4 + q][tp * 4]);
#pragma unroll
        for (int q = 0; q < 4; ++q) {
#pragma unroll
            for (int j = 0; j < 4; ++j) {
                const hf2 pj = P2[q].v[j];
#pragma unroll
                for (int i = 0; i < 8; ++i) {
                    hf2 d = F2[i].v[q] - pj;
                    unsigned ud = __builtin_bit_cast(unsigned, d) & 0x7FFF7FFFu;
                    acc[i][j] = FDOT2(__builtin_bit_cast(hf2, ud), one2, acc[i][j]);
                }
            }
        }
    }
    const int p = pb + tp * 4;
    if (p < 200) {
#pragma unroll
        for (int i = 0; i < 8; ++i) {
            float4 v = {-acc[i][0], -acc[i][1], -acc[i][2], -acc[i][3]};
            *(float4*)&part[((size_t)(rb + tr + 16 * i) * 8 + blockIdx.z) * 200 + p] = v;
        }
    }
}

__global__ __launch_bounds__(256) void l1_reduce(
    const float* __restrict__ part, float* __restrict__ out)
{
    const int row = blockIdx.x;
    const int p = threadIdx.x;
    if (p < 200) {
        float s = 0.f;
#pragma unroll
        for (int z = 0; z < 8; ++z)
            s += part[((size_t)row * 8 + z) * 200 + p];
        out[(size_t)row * 200 + p] = s;
    }
}

// ---------------------------------------------------------------------------
// Workspace layout (bytes). PART (13.1 MB) aliases GEMM-era scratch (incl.
// adFH at 11.96MB — adFH is dead before l1 writes part). featH/proH above.
// ---------------------------------------------------------------------------
static constexpr size_t OFF_PART  = 0;          // 2048 x 8 x 200 f32 partials
static constexpr size_t OFF_XB    = 0;          // 2048x768 bf16
static constexpr size_t OFF_AWB   = 3145728;
static constexpr size_t OFF_WD0   = 4325376;
static constexpr size_t OFF_WD1   = 4915200;
static constexpr size_t OFF_WD2   = 5062656;
static constexpr size_t OFF_WD3   = 5111808;
static constexpr size_t OFF_WU0   = 5128192;
static constexpr size_t OFF_WU1   = 5144576;
static constexpr size_t OFF_WU2   = 5193728;
static constexpr size_t OFF_WU3   = 5341184;
static constexpr size_t OFF_H1    = 5931008;    // 2048x384 bf16
static constexpr size_t OFF_U2    = 10387456;   // 2048x384 bf16
static constexpr size_t OFF_ADF   = 11960320;   // 2048x768 f16 (dead pre-l1)
static constexpr size_t OFF_FEATH = 19660800;   // 2048x768 f16
static constexpr size_t OFF_PROH  = 22806528;   // 256x768 f16

extern "C" void kernel_launch(void* const* d_in, const int* in_sizes, int n_in,
                              void* d_out, int out_size, void* d_ws, size_t ws_size,
                              hipStream_t stream) {
    const float* x      = (const float*)d_in[0];
    const float* aW     = (const float*)d_in[1];
    const float* ab     = (const float*)d_in[2];
    const float* protos = (const float*)d_in[3];
    const float* Wd[4]  = {(const float*)d_in[4], (const float*)d_in[6],
                           (const float*)d_in[8], (const float*)d_in[10]};
    const float* bd[4]  = {(const float*)d_in[5], (const float*)d_in[7],
                           (const float*)d_in[9], (const float*)d_in[11]};
    const float* Wu[4]  = {(const float*)d_in[12], (const float*)d_in[14],
                           (const float*)d_in[16], (const float*)d_in[18]};
    const float* bu[4]  = {(const float*)d_in[13], (const float*)d_in[15],
                           (const float*)d_in[17], (const float*)d_in[19]};
    float* out = (float*)d_out;
    char* ws = (char*)d_ws;

    u16* xb    = (u16*)(ws + OFF_XB);
    u16* aWb   = (u16*)(ws + OFF_AWB);
    u16* Wd0b  = (u16*)(ws + OFF_WD0);
    u16* Wd1b  = (u16*)(ws + OFF_WD1);
    u16* Wd2b  = (u16*)(ws + OFF_WD2);
    u16* Wd3b  = (u16*)(ws + OFF_WD3);
    u16* Wu0b  = (u16*)(ws + OFF_WU0);
    u16* Wu1b  = (u16*)(ws + OFF_WU1);
    u16* Wu2b  = (u16*)(ws + OFF_WU2);
    u16* Wu3b  = (u16*)(ws + OFF_WU3);
    u16* h1    = (u16*)(ws + OFF_H1);
    u16* u2    = (u16*)(ws + OFF_U2);
    float* part = (float*)(ws + OFF_PART);
    _Float16* adFH  = (_Float16*)(ws + OFF_ADF);
    _Float16* featH = (_Float16*)(ws + OFF_FEATH);
    _Float16* proH  = (_Float16*)(ws + OFF_PROH);

    const int SENT = 0x7FFFFFFF;

    // --- launch 1: cvt of launch-2 deps (x, Wd0, aW) ---
    CvtTab tabA;
    int blkA = 0;
    tabA.t[0] = {x,     xb,   2048, 768, 2048, 768, 0, 0};
    blkA += 2048 * 768 / 256;
    tabA.t[1] = {Wd[0], Wd0b, 384,  768, 384,  768, blkA, 0};
    blkA += 384 * 768 / 256;
    tabA.t[2] = {aW,    aWb,  768,  768, 768,  768, blkA, 0};
    blkA += 768 * 768 / 256;
    for (int j = 3; j < 11; ++j) tabA.t[j].blk0 = SENT;
    for (int r = 0; r < REPS; ++r)
        cvt_k<<<blkA, 256, 0, stream>>>(tabA);

    // --- launch 2: down0 (96) + adapter (192, -> adFH) + cvt of the rest ---
    CvtTab tabB;
    int blkB = 0;
    auto setB = [&](int i, const float* s, u16* d, int N, int K, int Np, int Kp,
                    int fmt) {
        tabB.t[i] = {s, d, N, K, Np, Kp, blkB, fmt};
        blkB += (Np * Kp + 255) / 256;
    };
    setB(0, Wd[1],  Wd1b,       192, 384, 192, 384, 0);
    setB(1, Wd[2],  Wd2b,       96,  192, 128, 192, 0);
    setB(2, Wd[3],  Wd3b,       48,  96,  64,  128, 0);
    setB(3, Wu[0],  Wu0b,       96,  48,  128, 64,  0);
    setB(4, Wu[1],  Wu1b,       192, 96,  192, 128, 0);
    setB(5, Wu[2],  Wu2b,       384, 192, 384, 192, 0);
    setB(6, Wu[3],  Wu3b,       768, 384, 768, 384, 0);
    setB(7, protos, (u16*)proH, 200, 768, 256, 768, 1);
    for (int j = 8; j < 11; ++j) tabB.t[j].blk0 = SENT;
    for (int r = 0; r < REPS; ++r)
        gemm_d0ad_cvt<<<288 + blkB, 256, 0, stream>>>(xb, Wd0b, bd[0], h1,
                                                      aWb, ab, adFH, tabB);

    // --- launch 3: chain d1..u2 ---
    for (int r = 0; r < REPS; ++r)
        chain512<<<128, 512, 0, stream>>>(h1,
            Wd1b, bd[1], Wd2b, bd[2], Wd3b, bd[3],
            Wu0b, bu[0], Wu1b, bu[1], Wu2b, bu[2], u2);

    // --- launch 4: featH = relu(u2@Wu3.T + bu3) + adFH ---
    for (int r = 0; r < REPS; ++r)
        gemm_u3<<<dim3(16, 12), 256, 0, stream>>>(u2, Wu3b, bu[3], adFH, featH);

    // --- launch 5+6: L1 head partials (z=8), then reduce ---
    for (int r = 0; r < REPS; ++r)
        l1_kernel<<<dim3(16, 4, 8), 256, 0, stream>>>(featH, proH, part);
    for (int r = 0; r < REPS; ++r)
        l1_reduce<<<dim3(2048), 256, 0, stream>>>(part, out);
}

// Round 15
// 159.300 us; speedup vs baseline: 3.9308x; 3.9308x over previous
//
#include <hip/hip_runtime.h>

typedef __attribute__((ext_vector_type(8))) __bf16 bf16x8;
typedef __attribute__((ext_vector_type(4))) float f32x4;
typedef __attribute__((ext_vector_type(4))) unsigned int u32x4;
typedef _Float16 hf2 __attribute__((ext_vector_type(2)));
typedef _Float16 hf8 __attribute__((ext_vector_type(8)));
typedef unsigned short u16;
typedef struct { hf2 v[4]; } hf2x4;   // register-friendly view of hf8

__device__ __forceinline__ float bf2f(u16 h) {
    return __uint_as_float(((unsigned int)h) << 16);
}
__device__ __forceinline__ u16 f2bf(float f) {
    unsigned int u = __float_as_uint(f);
    u += 0x7fffu + ((u >> 16) & 1u);   // RNE
    return (u16)(u >> 16);
}
// pack two f32 -> two bf16 (round-half-up; <=1/2 ulp vs RNE, inputs finite)
__device__ __forceinline__ unsigned pk_bf16_2(float a, float b) {
    unsigned ua = __float_as_uint(a) + 0x8000u;
    unsigned ub = __float_as_uint(b) + 0x8000u;
#if __has_builtin(__builtin_amdgcn_perm)
    return __builtin_amdgcn_perm(ub, ua, 0x07060302u);
#else
    return (ub & 0xFFFF0000u) | (ua >> 16);
#endif
}

#if __has_builtin(__builtin_amdgcn_fdot2)
__device__ __forceinline__ float FDOT2(hf2 a, hf2 b, float c) {
    return __builtin_amdgcn_fdot2(a, b, c, false);
}
#else
__device__ __forceinline__ float FDOT2(hf2 a, hf2 b, float c) {
    return c + (float)a[0] + (float)a[1];   // b is all-ones in our use
}
#endif

#define GLOAD_LDS16(gsrc, ldst)                                                          \
    __builtin_amdgcn_global_load_lds(                                                    \
        (__attribute__((address_space(1))) unsigned int*)(gsrc),                         \
        (__attribute__((address_space(3))) unsigned int*)(ldst), 16, 0, 0)

// ---------------------------------------------------------------------------
// f32 -> bf16/f16 convert with zero-padding. Unused tab entries: blk0=INT_MAX.
// ---------------------------------------------------------------------------
struct CvtDesc { const float* src; u16* dst; int N, K, Npad, Kpad, blk0, fmt; };
struct CvtTab { CvtDesc t[11]; };

__device__ __forceinline__ void do_cvt(const CvtTab& tab, int vb, int tid) {
    int ti = 0;
#pragma unroll
    for (int j = 1; j < 11; ++j)
        if (vb >= tab.t[j].blk0) ti = j;
    const CvtDesc c = tab.t[ti];
    long i = (long)(vb - c.blk0) * 256 + tid;
    long tot = (long)c.Npad * c.Kpad;
    if (i >= tot) return;
    int n = (int)(i / c.Kpad);
    int k = (int)(i - (long)n * c.Kpad);
    float v = (n < c.N && k < c.K) ? c.src[(long)n * c.K + k] : 0.f;
    c.dst[i] = c.fmt ? __builtin_bit_cast(u16, (_Float16)v) : f2bf(v);
}

// ---------------------------------------------------------------------------
// 128x64-tile double-buffered bf16 MFMA GEMM (bf16 sources, global_load_lds).
// ---------------------------------------------------------------------------
template<int RELU, int HASRES, int RESF16, int MODE>
__device__ __forceinline__ void gemm128_body(
    char* lds,
    const u16* __restrict__ A, int lda,
    const u16* __restrict__ W, int ldw,
    const float* __restrict__ bias,
    u16* __restrict__ outB, int ldo,
    const void* __restrict__ res, int ldr,
    _Float16* __restrict__ outH,
    int nk, int mb, int nb)
{
    const int tid = threadIdx.x;
    const int wave = tid >> 6, lane = tid & 63;
    const int lr = lane & 15, lk = lane >> 4;
    const int wr = wave >> 1, wc = wave & 1;

    f32x4 acc[4][2];
#pragma unroll
    for (int i = 0; i < 4; ++i)
#pragma unroll
        for (int j = 0; j < 2; ++j)
#pragma unroll
            for (int e = 0; e < 4; ++e) acc[i][j][e] = 0.f;

    int ra[4], la[4], rb_[2], lb[2];
#pragma unroll
    for (int t = 0; t < 4; ++t) {
        int g = t * 256 + tid;
        ra[t] = g >> 3; la[t] = (g & 7) ^ (ra[t] & 7);
    }
#pragma unroll
    for (int t = 0; t < 2; ++t) {
        int g = t * 256 + tid;
        rb_[t] = g >> 3; lb[t] = (g & 7) ^ (rb_[t] & 7);
    }

    auto STAGE = [&](int b, int kt) {
        const int kk = kt * 64;
        char* dA = lds + b * 24576;
        char* dB = dA + 16384;
#pragma unroll
        for (int t = 0; t < 4; ++t)
            GLOAD_LDS16(A + (size_t)(mb + ra[t]) * lda + kk + la[t] * 8,
                        dA + t * 4096 + wave * 1024);
#pragma unroll
        for (int t = 0; t < 2; ++t)
            GLOAD_LDS16(W + (size_t)(nb + rb_[t]) * ldw + kk + lb[t] * 8,
                        dB + t * 4096 + wave * 1024);
    };
    auto COMPUTE = [&](int b) {
        char* sA = lds + b * 24576;
        char* sB = sA + 16384;
#pragma unroll
        for (int ks = 0; ks < 2; ++ks) {
            bf16x8 af[4], bfr[2];
#pragma unroll
            for (int mi = 0; mi < 4; ++mi) {
                int m_loc = wr * 64 + mi * 16 + lr;
                int gr = (ks * 4 + lk) ^ (m_loc & 7);
                af[mi] = *(const bf16x8*)(sA + m_loc * 128 + gr * 16);
            }
#pragma unroll
            for (int ni = 0; ni < 2; ++ni) {
                int n_loc = wc * 32 + ni * 16 + lr;
                int gr = (ks * 4 + lk) ^ (n_loc & 7);
                bfr[ni] = *(const bf16x8*)(sB + n_loc * 128 + gr * 16);
            }
#pragma unroll
            for (int mi = 0; mi < 4; ++mi)
#pragma unroll
                for (int ni = 0; ni < 2; ++ni)
                    acc[mi][ni] = __builtin_amdgcn_mfma_f32_16x16x32_bf16(
                        af[mi], bfr[ni], acc[mi][ni], 0, 0, 0);
        }
    };

    STAGE(0, 0);
    __syncthreads();
    int b = 0;
    for (int kt = 0; kt < nk - 1; ++kt) {
        STAGE(b ^ 1, kt + 1);
        COMPUTE(b);
        __syncthreads();
        b ^= 1;
    }
    COMPUTE(b);

#pragma unroll
    for (int mi = 0; mi < 4; ++mi) {
#pragma unroll
        for (int ni = 0; ni < 2; ++ni) {
            const int n_g = nb + wc * 32 + ni * 16 + lr;
            const float bv = bias[n_g];
#pragma unroll
            for (int r = 0; r < 4; ++r) {
                const int m_g = mb + wr * 64 + mi * 16 + lk * 4 + r;
                float v = acc[mi][ni][r] + bv;
                if (RELU) v = fmaxf(v, 0.f);
                if (HASRES) {
                    if (RESF16)
                        v += (float)((const _Float16*)res)[(size_t)m_g * ldr + n_g];
                    else
                        v += bf2f(((const u16*)res)[(size_t)m_g * ldr + n_g]);
                }
                if (MODE == 2) outH[(size_t)m_g * 768 + n_g] = (_Float16)v;
                else           outB[(size_t)m_g * ldo + n_g] = f2bf(v);
            }
        }
    }
}

// ---------------------------------------------------------------------------
// 128x64-tile dbuf GEMM with F32 SOURCES: reg-staged (load f32 -> pack bf16
// -> ds_write_b128), T14 split: LOAD(next) / COMPUTE(cur) / WRITE(next).
// LDS layout + swizzle + COMPUTE identical to gemm128_body (verified).
// HASRES adds f32 res (stride lda). MODE 0 -> bf16 outB, 2 -> f16 outH.
// ---------------------------------------------------------------------------
template<int RELU, int HASRES, int MODE>
__device__ __forceinline__ void gemm128_f32(
    char* lds,
    const float* __restrict__ A, int lda,
    const float* __restrict__ W, int ldw,
    const float* __restrict__ bias,
    u16* __restrict__ outB, int ldo,
    const float* __restrict__ res,
    _Float16* __restrict__ outH,
    int nk, int mb, int nb)
{
    const int tid = threadIdx.x;
    const int wave = tid >> 6, lane = tid & 63;
    const int lr = lane & 15, lk = lane >> 4;
    const int wr = wave >> 1, wc = wave & 1;

    f32x4 acc[4][2];
#pragma unroll
    for (int i = 0; i < 4; ++i)
#pragma unroll
        for (int j = 0; j < 2; ++j)
#pragma unroll
            for (int e = 0; e < 4; ++e) acc[i][j][e] = 0.f;

    int ra[4], la[4], rb_[2], lb[2];
#pragma unroll
    for (int t = 0; t < 4; ++t) {
        int g = t * 256 + tid;
        ra[t] = g >> 3; la[t] = (g & 7) ^ (ra[t] & 7);
    }
#pragma unroll
    for (int t = 0; t < 2; ++t) {
        int g = t * 256 + tid;
        rb_[t] = g >> 3; lb[t] = (g & 7) ^ (rb_[t] & 7);
    }

    float4 rA[4][2], rB[2][2];
    auto LOADT = [&](int kt) {
        const int kk = kt * 64;
#pragma unroll
        for (int t = 0; t < 4; ++t) {
            const float* p = A + (size_t)(mb + ra[t]) * lda + kk + la[t] * 8;
            rA[t][0] = *(const float4*)p;
            rA[t][1] = *(const float4*)(p + 4);
        }
#pragma unroll
        for (int t = 0; t < 2; ++t) {
            const float* p = W + (size_t)(nb + rb_[t]) * ldw + kk + lb[t] * 8;
            rB[t][0] = *(const float4*)p;
            rB[t][1] = *(const float4*)(p + 4);
        }
    };
    auto PACK = [&](float4 lo, float4 hi) -> u32x4 {
        u32x4 r;
        r[0] = pk_bf16_2(lo.x, lo.y);
        r[1] = pk_bf16_2(lo.z, lo.w);
        r[2] = pk_bf16_2(hi.x, hi.y);
        r[3] = pk_bf16_2(hi.z, hi.w);
        return r;
    };
    auto WRITET = [&](int b) {
        char* dA = lds + b * 24576;
        char* dB = dA + 16384;
#pragma unroll
        for (int t = 0; t < 4; ++t)
            *(u32x4*)(dA + t * 4096 + wave * 1024 + lane * 16) = PACK(rA[t][0], rA[t][1]);
#pragma unroll
        for (int t = 0; t < 2; ++t)
            *(u32x4*)(dB + t * 4096 + wave * 1024 + lane * 16) = PACK(rB[t][0], rB[t][1]);
    };
    auto COMPUTE = [&](int b) {
        char* sA = lds + b * 24576;
        char* sB = sA + 16384;
#pragma unroll
        for (int ks = 0; ks < 2; ++ks) {
            bf16x8 af[4], bfr[2];
#pragma unroll
            for (int mi = 0; mi < 4; ++mi) {
                int m_loc = wr * 64 + mi * 16 + lr;
                int gr = (ks * 4 + lk) ^ (m_loc & 7);
                af[mi] = *(const bf16x8*)(sA + m_loc * 128 + gr * 16);
            }
#pragma unroll
            for (int ni = 0; ni < 2; ++ni) {
                int n_loc = wc * 32 + ni * 16 + lr;
                int gr = (ks * 4 + lk) ^ (n_loc & 7);
                bfr[ni] = *(const bf16x8*)(sB + n_loc * 128 + gr * 16);
            }
#pragma unroll
            for (int mi = 0; mi < 4; ++mi)
#pragma unroll
                for (int ni = 0; ni < 2; ++ni)
                    acc[mi][ni] = __builtin_amdgcn_mfma_f32_16x16x32_bf16(
                        af[mi], bfr[ni], acc[mi][ni], 0, 0, 0);
        }
    };

    LOADT(0);
    WRITET(0);
    __syncthreads();
    int b = 0;
    for (int kt = 0; kt < nk - 1; ++kt) {
        LOADT(kt + 1);     // issue early: latency hides under COMPUTE
        COMPUTE(b);
        WRITET(b ^ 1);     // waits loads, packs, ds_writes
        __syncthreads();
        b ^= 1;
    }
    COMPUTE(b);

#pragma unroll
    for (int mi = 0; mi < 4; ++mi) {
#pragma unroll
        for (int ni = 0; ni < 2; ++ni) {
            const int n_g = nb + wc * 32 + ni * 16 + lr;
            const float bv = bias[n_g];
#pragma unroll
            for (int r = 0; r < 4; ++r) {
                const int m_g = mb + wr * 64 + mi * 16 + lk * 4 + r;
                float v = acc[mi][ni][r] + bv;
                if (RELU) v = fmaxf(v, 0.f);
                if (HASRES) v += res[(size_t)m_g * lda + n_g];
                if (MODE == 2) outH[(size_t)m_g * 768 + n_g] = (_Float16)v;
                else           outB[(size_t)m_g * ldo + n_g] = f2bf(v);
            }
        }
    }
}

// ---------------------------------------------------------------------------
// launch 1: down0 (96 tiles, f32 src) + adapter (192 tiles, f32 src:
// adFH = f16(x@aW.T + ab + x)) + cvt of chain/u3 weights + protos
// + zero the l1 completion counters. No separate cvt launch needed.
// ---------------------------------------------------------------------------
__global__ __launch_bounds__(256, 2) void gemm_d0ad_cvt(
    const float* __restrict__ x, const float* __restrict__ Wd0,
    const float* __restrict__ bd0, u16* __restrict__ h1,
    const float* __restrict__ aW, const float* __restrict__ ab,
    _Float16* __restrict__ adFH, CvtTab tabB, unsigned int* __restrict__ cnt)
{
    __shared__ __align__(16) char lds[49152];
    const int bid = blockIdx.x;
    if (bid == 0 && threadIdx.x < 64) cnt[threadIdx.x] = 0u;
    if (bid < 96) {
        gemm128_f32<1, 0, 0>(lds, x, 768, Wd0, 768, bd0, h1, 384,
                             nullptr, nullptr, 12,
                             (bid & 15) * 128, (bid >> 4) * 64);
    } else if (bid < 288) {
        const int b2 = bid - 96;
        gemm128_f32<0, 1, 2>(lds, x, 768, aW, 768, ab, nullptr, 0,
                             x, adFH, 12,
                             (b2 & 15) * 128, (b2 >> 4) * 64);
    } else {
        do_cvt(tabB, bid - 288, threadIdx.x);
    }
}

// ---------------------------------------------------------------------------
// chain512: d1..u2, 128 blocks x 512 thr (8 waves = 4 N-waves x 2 K-waves).
// ---------------------------------------------------------------------------
template<int K, int NPAD, int NREAL, int RES, int OUTG>
__device__ __forceinline__ void layer16s(
    const u16* __restrict__ W, int ldw, const float* __restrict__ bias,
    const u16* actIn, int ldin,
    u16* actOut, int ldout,
    const u16* resid, int ldres,
    u16* __restrict__ gout, int ldg,
    float* comb)
{
    constexpr int TPW = NPAD / 64;
    constexpr int KK = K / 32;
    constexpr int KH = KK / 2;
    const int tid = threadIdx.x;
    const int w = tid >> 6, lane = tid & 63;
    const int nw = w & 3, kw = w >> 2;
    const int lr = lane & 15, lk = lane >> 4;

    f32x4 acc[TPW];
#pragma unroll
    for (int t = 0; t < TPW; ++t)
#pragma unroll
        for (int e = 0; e < 4; ++e) acc[t][e] = 0.f;

#pragma unroll
    for (int s = 0; s < KH; ++s) {
        const int kk = kw * KH + s;
        const bf16x8 a = *(const bf16x8*)&actIn[lr * ldin + kk * 32 + lk * 8];
#pragma unroll
        for (int t = 0; t < TPW; ++t) {
            const int nc = (nw * TPW + t) * 16 + lr;
            const bf16x8 b = *(const bf16x8*)&W[(size_t)nc * ldw + kk * 32 + lk * 8];
            acc[t] = __builtin_amdgcn_mfma_f32_16x16x32_bf16(a, b, acc[t], 0, 0, 0);
        }
    }
    if (kw == 1) {
#pragma unroll
        for (int t = 0; t < TPW; ++t)
            *(f32x4*)(comb + ((size_t)(nw * TPW + t) * 64 + lane) * 4) = acc[t];
    }
    __syncthreads();
    if (kw == 0) {
#pragma unroll
        for (int t = 0; t < TPW; ++t) {
            const f32x4 o = *(const f32x4*)(comb + ((size_t)(nw * TPW + t) * 64 + lane) * 4);
            const int nc = (nw * TPW + t) * 16 + lr;
            const float bv = (nc < NREAL) ? bias[nc] : 0.f;
#pragma unroll
            for (int r = 0; r < 4; ++r) {
                const int row = lk * 4 + r;
                float v = fmaxf(acc[t][r] + o[r] + bv, 0.f);
                if (RES) v += bf2f(resid[row * ldres + nc]);
                const u16 ov = f2bf(v);
                if (OUTG) gout[(size_t)row * ldg + nc] = ov;
                else      actOut[row * ldout + nc] = ov;
            }
        }
    }
    __syncthreads();
}

__global__ __launch_bounds__(512) void chain512(
    const u16* __restrict__ h1,
    const u16* __restrict__ Wd1b, const float* __restrict__ bd1,
    const u16* __restrict__ Wd2b, const float* __restrict__ bd2,
    const u16* __restrict__ Wd3b, const float* __restrict__ bd3,
    const u16* __restrict__ Wu0b, const float* __restrict__ bu0,
    const u16* __restrict__ Wu1b, const float* __restrict__ bu1,
    const u16* __restrict__ Wu2b, const float* __restrict__ bu2,
    u16* __restrict__ u2)
{
    __shared__ u16 As[16 * 392];
    __shared__ u16 Bs[16 * 200];
    __shared__ u16 Cs[16 * 136];
    __shared__ u16 Ds[16 * 72];
    __shared__ float comb[6144];      // 24 tiles x 64 lanes x f32x4 = 24576 B
    const int tid = threadIdx.x;
    const int rb = blockIdx.x * 16;

    for (int i = tid; i < 768; i += 512) {
        const int r = i / 48, c = i - r * 48;
        *(bf16x8*)&As[r * 392 + c * 8] =
            *(const bf16x8*)&h1[(size_t)(rb + r) * 384 + c * 8];
    }
    __syncthreads();
    layer16s<384, 192, 192, 0, 0>(Wd1b, 384, bd1, As, 392, Bs, 200, nullptr, 0, nullptr, 0, comb);
    layer16s<192, 128,  96, 0, 0>(Wd2b, 192, bd2, Bs, 200, Cs, 136, nullptr, 0, nullptr, 0, comb);
    layer16s<128,  64,  48, 0, 0>(Wd3b, 128, bd3, Cs, 136, Ds,  72, nullptr, 0, nullptr, 0, comb);
    u16* E = As;
    u16* F = As + 16 * 136;
    layer16s< 64, 128,  96, 1, 0>(Wu0b,  64, bu0, Ds,  72, E, 136, Cs, 136, nullptr, 0, comb);
    layer16s<128, 192, 192, 1, 0>(Wu1b, 128, bu1, E, 136, F, 200, Bs, 200, nullptr, 0, comb);
    layer16s<192, 384, 384, 0, 1>(Wu2b, 192, bu2, F, 200, nullptr, 0, nullptr, 0,
                                  u2 + (size_t)rb * 384, 384, comb);
}

// launch 3: featH = f16( relu(u2@Wu3.T + bu3) + adFH )
__global__ __launch_bounds__(256, 2) void gemm_u3(
    const u16* __restrict__ u2, const u16* __restrict__ Wu3b,
    const float* __restrict__ bu3, const _Float16* __restrict__ adFH,
    _Float16* __restrict__ featH)
{
    __shared__ __align__(16) char lds[49152];
    gemm128_body<1, 1, 1, 2>(lds, u2, 384, Wu3b, 384, bu3, nullptr, 0,
                             adFH, 768, featH, 6,
                             blockIdx.x * 128, blockIdx.y * 64);
}

// ---------------------------------------------------------------------------
// launch 4: L1 head with FUSED reduction.
// part[row][z][p] = -sum_{d in 96-chunk z} |feat-proto| (non-atomic stores);
// per-(rb,pb) completion counter; the 8th z-block sums over z -> out.
// ---------------------------------------------------------------------------
__global__ __launch_bounds__(256) void l1_fused(
    const _Float16* __restrict__ feat, const _Float16* __restrict__ protos,
    float* __restrict__ part, float* __restrict__ out,
    unsigned int* __restrict__ cnt)
{
    __shared__ _Float16 fs[128][96];   // 24576 B
    __shared__ hf2 pt[48][64];         // 12288 B  [d-pair][proto]
    __shared__ unsigned int last;
    const int tid = threadIdx.x;
    const int tp = tid & 15, tr = tid >> 4;
    const int rb = blockIdx.x * 128;
    const int pb = blockIdx.y * 64;
    const int db = blockIdx.z * 96;

    for (int i = tid; i < 1536; i += 256) {
        const int r = i / 12, c = i - r * 12;
        *(hf8*)&fs[r][c * 8] =
            *(const hf8*)&feat[(size_t)(rb + r) * 768 + db + c * 8];
    }
    {
        const int sp = tid & 63, q = tid >> 6;
#pragma unroll
        for (int t = 0; t < 3; ++t) {
            const hf8 v = *(const hf8*)&protos[(size_t)(pb + sp) * 768 + db + q * 24 + t * 8];
            const hf2x4 w = __builtin_bit_cast(hf2x4, v);
            const int p0 = q * 12 + t * 4;
#pragma unroll
            for (int e = 0; e < 4; ++e)
                pt[p0 + e][sp] = w.v[e];
        }
    }
    __syncthreads();

    float acc[8][4];
#pragma unroll
    for (int i = 0; i < 8; ++i)
#pragma unroll
        for (int j = 0; j < 4; ++j) acc[i][j] = 0.f;

    const hf2 one2 = {(_Float16)1.0f, (_Float16)1.0f};
#pragma unroll 2
    for (int g = 0; g < 12; ++g) {
        hf2x4 F2[8];
#pragma unroll
        for (int i = 0; i < 8; ++i)
            F2[i] = __builtin_bit_cast(hf2x4, *(const hf8*)&fs[tr + 16 * i][g * 8]);
        hf2x4 P2[4];
#pragma unroll
        for (int q = 0; q < 4; ++q)
            P2[q] = __builtin_bit_cast(hf2x4, *(const hf8*)&pt[g * 4 + q][tp * 4]);
#pragma unroll
        for (int q = 0; q < 4; ++q) {
#pragma unroll
            for (int j = 0; j < 4; ++j) {
                const hf2 pj = P2[q].v[j];
#pragma unroll
                for (int i = 0; i < 8; ++i) {
                    hf2 d = F2[i].v[q] - pj;
                    unsigned ud = __builtin_bit_cast(unsigned, d) & 0x7FFF7FFFu;
                    acc[i][j] = FDOT2(__builtin_bit_cast(hf2, ud), one2, acc[i][j]);
                }
            }
        }
    }
    const int p = pb + tp * 4;
    if (p < 200) {
#pragma unroll
        for (int i = 0; i < 8; ++i) {
            float4 v = {-acc[i][0], -acc[i][1], -acc[i][2], -acc[i][3]};
            *(float4*)&part[((size_t)(rb + tr + 16 * i) * 8 + blockIdx.z) * 200 + p] = v;
        }
    }

    // fused reduction: last z-block of this (rb,pb) sums over z
    __threadfence();                                  // release our stores
    if (tid == 0)
        last = atomicAdd(&cnt[blockIdx.x * 4 + blockIdx.y], 1u);
    __syncthreads();
    if (last == 7u) {
        __threadfence();                              // acquire others' stores
        const int co = tid & 63;
        const int pp = pb + co;
        if (pp < 200) {
#pragma unroll 4
            for (int i = 0; i < 32; ++i) {
                const int row = rb + (tid >> 6) + 4 * i;
                float s = 0.f;
#pragma unroll
                for (int z = 0; z < 8; ++z)
                    s += part[((size_t)row * 8 + z) * 200 + pp];
                out[(size_t)row * 200 + pp] = s;
            }
        }
    }
}

// ---------------------------------------------------------------------------
// Workspace layout (bytes). PART (13.1 MB) aliases chain/u3 weights (dead by
// the time l1 runs). featH/proH/cnt live above. x/aW/Wd0 read as f32 inputs.
// ---------------------------------------------------------------------------
static constexpr size_t OFF_PART  = 0;          // 2048 x 8 x 200 f32 partials
static constexpr size_t OFF_WD1   = 4915200;
static constexpr size_t OFF_WD2   = 5062656;
static constexpr size_t OFF_WD3   = 5111808;
static constexpr size_t OFF_WU0   = 5128192;
static constexpr size_t OFF_WU1   = 5144576;
static constexpr size_t OFF_WU2   = 5193728;
static constexpr size_t OFF_WU3   = 5341184;
static constexpr size_t OFF_H1    = 5931008;    // 2048x384 bf16
static constexpr size_t OFF_U2    = 10387456;   // 2048x384 bf16
static constexpr size_t OFF_ADF   = 11960320;   // 2048x768 f16 (dead pre-l1)
static constexpr size_t OFF_FEATH = 19660800;   // 2048x768 f16
static constexpr size_t OFF_PROH  = 22806528;   // 256x768 f16
static constexpr size_t OFF_CNT   = 23199744;   // 64 x u32 completion counters

extern "C" void kernel_launch(void* const* d_in, const int* in_sizes, int n_in,
                              void* d_out, int out_size, void* d_ws, size_t ws_size,
                              hipStream_t stream) {
    const float* x      = (const float*)d_in[0];
    const float* aW     = (const float*)d_in[1];
    const float* ab     = (const float*)d_in[2];
    const float* protos = (const float*)d_in[3];
    const float* Wd[4]  = {(const float*)d_in[4], (const float*)d_in[6],
                           (const float*)d_in[8], (const float*)d_in[10]};
    const float* bd[4]  = {(const float*)d_in[5], (const float*)d_in[7],
                           (const float*)d_in[9], (const float*)d_in[11]};
    const float* Wu[4]  = {(const float*)d_in[12], (const float*)d_in[14],
                           (const float*)d_in[16], (const float*)d_in[18]};
    const float* bu[4]  = {(const float*)d_in[13], (const float*)d_in[15],
                           (const float*)d_in[17], (const float*)d_in[19]};
    float* out = (float*)d_out;
    char* ws = (char*)d_ws;

    u16* Wd1b  = (u16*)(ws + OFF_WD1);
    u16* Wd2b  = (u16*)(ws + OFF_WD2);
    u16* Wd3b  = (u16*)(ws + OFF_WD3);
    u16* Wu0b  = (u16*)(ws + OFF_WU0);
    u16* Wu1b  = (u16*)(ws + OFF_WU1);
    u16* Wu2b  = (u16*)(ws + OFF_WU2);
    u16* Wu3b  = (u16*)(ws + OFF_WU3);
    u16* h1    = (u16*)(ws + OFF_H1);
    u16* u2    = (u16*)(ws + OFF_U2);
    float* part = (float*)(ws + OFF_PART);
    _Float16* adFH  = (_Float16*)(ws + OFF_ADF);
    _Float16* featH = (_Float16*)(ws + OFF_FEATH);
    _Float16* proH  = (_Float16*)(ws + OFF_PROH);
    unsigned int* cnt = (unsigned int*)(ws + OFF_CNT);

    const int SENT = 0x7FFFFFFF;

    // --- launch 1: down0 + adapter (f32 sources) + cvt of chain/u3/proto ---
    CvtTab tabB;
    int blkB = 0;
    auto setB = [&](int i, const float* s, u16* d, int N, int K, int Np, int Kp,
                    int fmt) {
        tabB.t[i] = {s, d, N, K, Np, Kp, blkB, fmt};
        blkB += (Np * Kp + 255) / 256;
    };
    setB(0, Wd[1],  Wd1b,       192, 384, 192, 384, 0);
    setB(1, Wd[2],  Wd2b,       96,  192, 128, 192, 0);
    setB(2, Wd[3],  Wd3b,       48,  96,  64,  128, 0);
    setB(3, Wu[0],  Wu0b,       96,  48,  128, 64,  0);
    setB(4, Wu[1],  Wu1b,       192, 96,  192, 128, 0);
    setB(5, Wu[2],  Wu2b,       384, 192, 384, 192, 0);
    setB(6, Wu[3],  Wu3b,       768, 384, 768, 384, 0);
    setB(7, protos, (u16*)proH, 200, 768, 256, 768, 1);
    for (int j = 8; j < 11; ++j) tabB.t[j].blk0 = SENT;
    gemm_d0ad_cvt<<<288 + blkB, 256, 0, stream>>>(x, Wd[0], bd[0], h1,
                                                  aW, ab, adFH, tabB, cnt);

    // --- launch 2: chain d1..u2 ---
    chain512<<<128, 512, 0, stream>>>(h1,
        Wd1b, bd[1], Wd2b, bd[2], Wd3b, bd[3],
        Wu0b, bu[0], Wu1b, bu[1], Wu2b, bu[2], u2);

    // --- launch 3: featH = relu(u2@Wu3.T + bu3) + adFH ---
    gemm_u3<<<dim3(16, 12), 256, 0, stream>>>(u2, Wu3b, bu[3], adFH, featH);

    // --- launch 4: L1 head partials + fused reduction ---
    l1_fused<<<dim3(16, 4, 8), 256, 0, stream>>>(featH, proH, part, out, cnt);
}

// Round 16
// 78.564 us; speedup vs baseline: 7.9703x; 2.0276x over previous
//
#include <hip/hip_runtime.h>

typedef __attribute__((ext_vector_type(8))) __bf16 bf16x8;
typedef __attribute__((ext_vector_type(4))) float f32x4;
typedef __attribute__((ext_vector_type(4))) unsigned int u32x4;
typedef _Float16 hf2 __attribute__((ext_vector_type(2)));
typedef _Float16 hf8 __attribute__((ext_vector_type(8)));
typedef unsigned short u16;
typedef struct { hf2 v[4]; } hf2x4;   // register-friendly view of hf8

__device__ __forceinline__ float bf2f(u16 h) {
    return __uint_as_float(((unsigned int)h) << 16);
}
__device__ __forceinline__ u16 f2bf(float f) {
    unsigned int u = __float_as_uint(f);
    u += 0x7fffu + ((u >> 16) & 1u);   // RNE
    return (u16)(u >> 16);
}
// pack two f32 -> two bf16 (round-half-up; <=1/2 ulp vs RNE, inputs finite)
__device__ __forceinline__ unsigned pk_bf16_2(float a, float b) {
    unsigned ua = __float_as_uint(a) + 0x8000u;
    unsigned ub = __float_as_uint(b) + 0x8000u;
#if __has_builtin(__builtin_amdgcn_perm)
    return __builtin_amdgcn_perm(ub, ua, 0x07060302u);
#else
    return (ub & 0xFFFF0000u) | (ua >> 16);
#endif
}

#if __has_builtin(__builtin_amdgcn_fdot2)
__device__ __forceinline__ float FDOT2(hf2 a, hf2 b, float c) {
    return __builtin_amdgcn_fdot2(a, b, c, false);
}
#else
__device__ __forceinline__ float FDOT2(hf2 a, hf2 b, float c) {
    return c + (float)a[0] + (float)a[1];   // b is all-ones in our use
}
#endif

#define GLOAD_LDS16(gsrc, ldst)                                                          \
    __builtin_amdgcn_global_load_lds(                                                    \
        (__attribute__((address_space(1))) unsigned int*)(gsrc),                         \
        (__attribute__((address_space(3))) unsigned int*)(ldst), 16, 0, 0)

// ---------------------------------------------------------------------------
// f32 -> bf16/f16 convert with zero-padding. Unused tab entries: blk0=INT_MAX.
// ---------------------------------------------------------------------------
struct CvtDesc { const float* src; u16* dst; int N, K, Npad, Kpad, blk0, fmt; };
struct CvtTab { CvtDesc t[11]; };

__device__ __forceinline__ void do_cvt(const CvtTab& tab, int vb, int tid) {
    int ti = 0;
#pragma unroll
    for (int j = 1; j < 11; ++j)
        if (vb >= tab.t[j].blk0) ti = j;
    const CvtDesc c = tab.t[ti];
    long i = (long)(vb - c.blk0) * 256 + tid;
    long tot = (long)c.Npad * c.Kpad;
    if (i >= tot) return;
    int n = (int)(i / c.Kpad);
    int k = (int)(i - (long)n * c.Kpad);
    float v = (n < c.N && k < c.K) ? c.src[(long)n * c.K + k] : 0.f;
    c.dst[i] = c.fmt ? __builtin_bit_cast(u16, (_Float16)v) : f2bf(v);
}

// ---------------------------------------------------------------------------
// 128x64-tile double-buffered bf16 MFMA GEMM (bf16 sources, global_load_lds).
// ---------------------------------------------------------------------------
template<int RELU, int HASRES, int RESF16, int MODE>
__device__ __forceinline__ void gemm128_body(
    char* lds,
    const u16* __restrict__ A, int lda,
    const u16* __restrict__ W, int ldw,
    const float* __restrict__ bias,
    u16* __restrict__ outB, int ldo,
    const void* __restrict__ res, int ldr,
    _Float16* __restrict__ outH,
    int nk, int mb, int nb)
{
    const int tid = threadIdx.x;
    const int wave = tid >> 6, lane = tid & 63;
    const int lr = lane & 15, lk = lane >> 4;
    const int wr = wave >> 1, wc = wave & 1;

    f32x4 acc[4][2];
#pragma unroll
    for (int i = 0; i < 4; ++i)
#pragma unroll
        for (int j = 0; j < 2; ++j)
#pragma unroll
            for (int e = 0; e < 4; ++e) acc[i][j][e] = 0.f;

    int ra[4], la[4], rb_[2], lb[2];
#pragma unroll
    for (int t = 0; t < 4; ++t) {
        int g = t * 256 + tid;
        ra[t] = g >> 3; la[t] = (g & 7) ^ (ra[t] & 7);
    }
#pragma unroll
    for (int t = 0; t < 2; ++t) {
        int g = t * 256 + tid;
        rb_[t] = g >> 3; lb[t] = (g & 7) ^ (rb_[t] & 7);
    }

    auto STAGE = [&](int b, int kt) {
        const int kk = kt * 64;
        char* dA = lds + b * 24576;
        char* dB = dA + 16384;
#pragma unroll
        for (int t = 0; t < 4; ++t)
            GLOAD_LDS16(A + (size_t)(mb + ra[t]) * lda + kk + la[t] * 8,
                        dA + t * 4096 + wave * 1024);
#pragma unroll
        for (int t = 0; t < 2; ++t)
            GLOAD_LDS16(W + (size_t)(nb + rb_[t]) * ldw + kk + lb[t] * 8,
                        dB + t * 4096 + wave * 1024);
    };
    auto COMPUTE = [&](int b) {
        char* sA = lds + b * 24576;
        char* sB = sA + 16384;
#pragma unroll
        for (int ks = 0; ks < 2; ++ks) {
            bf16x8 af[4], bfr[2];
#pragma unroll
            for (int mi = 0; mi < 4; ++mi) {
                int m_loc = wr * 64 + mi * 16 + lr;
                int gr = (ks * 4 + lk) ^ (m_loc & 7);
                af[mi] = *(const bf16x8*)(sA + m_loc * 128 + gr * 16);
            }
#pragma unroll
            for (int ni = 0; ni < 2; ++ni) {
                int n_loc = wc * 32 + ni * 16 + lr;
                int gr = (ks * 4 + lk) ^ (n_loc & 7);
                bfr[ni] = *(const bf16x8*)(sB + n_loc * 128 + gr * 16);
            }
#pragma unroll
            for (int mi = 0; mi < 4; ++mi)
#pragma unroll
                for (int ni = 0; ni < 2; ++ni)
                    acc[mi][ni] = __builtin_amdgcn_mfma_f32_16x16x32_bf16(
                        af[mi], bfr[ni], acc[mi][ni], 0, 0, 0);
        }
    };

    STAGE(0, 0);
    __syncthreads();
    int b = 0;
    for (int kt = 0; kt < nk - 1; ++kt) {
        STAGE(b ^ 1, kt + 1);
        COMPUTE(b);
        __syncthreads();
        b ^= 1;
    }
    COMPUTE(b);

#pragma unroll
    for (int mi = 0; mi < 4; ++mi) {
#pragma unroll
        for (int ni = 0; ni < 2; ++ni) {
            const int n_g = nb + wc * 32 + ni * 16 + lr;
            const float bv = bias[n_g];
#pragma unroll
            for (int r = 0; r < 4; ++r) {
                const int m_g = mb + wr * 64 + mi * 16 + lk * 4 + r;
                float v = acc[mi][ni][r] + bv;
                if (RELU) v = fmaxf(v, 0.f);
                if (HASRES) {
                    if (RESF16)
                        v += (float)((const _Float16*)res)[(size_t)m_g * ldr + n_g];
                    else
                        v += bf2f(((const u16*)res)[(size_t)m_g * ldr + n_g]);
                }
                if (MODE == 2) outH[(size_t)m_g * 768 + n_g] = (_Float16)v;
                else           outB[(size_t)m_g * ldo + n_g] = f2bf(v);
            }
        }
    }
}

// ---------------------------------------------------------------------------
// 128x64-tile dbuf GEMM with F32 SOURCES: reg-staged (load f32 -> pack bf16
// -> ds_write_b128), T14 split: LOAD(next) / COMPUTE(cur) / WRITE(next).
// LDS layout + swizzle + COMPUTE identical to gemm128_body (verified).
// HASRES adds f32 res (stride lda). MODE 0 -> bf16 outB, 2 -> f16 outH.
// ---------------------------------------------------------------------------
template<int RELU, int HASRES, int MODE>
__device__ __forceinline__ void gemm128_f32(
    char* lds,
    const float* __restrict__ A, int lda,
    const float* __restrict__ W, int ldw,
    const float* __restrict__ bias,
    u16* __restrict__ outB, int ldo,
    const float* __restrict__ res,
    _Float16* __restrict__ outH,
    int nk, int mb, int nb)
{
    const int tid = threadIdx.x;
    const int wave = tid >> 6, lane = tid & 63;
    const int lr = lane & 15, lk = lane >> 4;
    const int wr = wave >> 1, wc = wave & 1;

    f32x4 acc[4][2];
#pragma unroll
    for (int i = 0; i < 4; ++i)
#pragma unroll
        for (int j = 0; j < 2; ++j)
#pragma unroll
            for (int e = 0; e < 4; ++e) acc[i][j][e] = 0.f;

    int ra[4], la[4], rb_[2], lb[2];
#pragma unroll
    for (int t = 0; t < 4; ++t) {
        int g = t * 256 + tid;
        ra[t] = g >> 3; la[t] = (g & 7) ^ (ra[t] & 7);
    }
#pragma unroll
    for (int t = 0; t < 2; ++t) {
        int g = t * 256 + tid;
        rb_[t] = g >> 3; lb[t] = (g & 7) ^ (rb_[t] & 7);
    }

    float4 rA[4][2], rB[2][2];
    auto LOADT = [&](int kt) {
        const int kk = kt * 64;
#pragma unroll
        for (int t = 0; t < 4; ++t) {
            const float* p = A + (size_t)(mb + ra[t]) * lda + kk + la[t] * 8;
            rA[t][0] = *(const float4*)p;
            rA[t][1] = *(const float4*)(p + 4);
        }
#pragma unroll
        for (int t = 0; t < 2; ++t) {
            const float* p = W + (size_t)(nb + rb_[t]) * ldw + kk + lb[t] * 8;
            rB[t][0] = *(const float4*)p;
            rB[t][1] = *(const float4*)(p + 4);
        }
    };
    auto PACK = [&](float4 lo, float4 hi) -> u32x4 {
        u32x4 r;
        r[0] = pk_bf16_2(lo.x, lo.y);
        r[1] = pk_bf16_2(lo.z, lo.w);
        r[2] = pk_bf16_2(hi.x, hi.y);
        r[3] = pk_bf16_2(hi.z, hi.w);
        return r;
    };
    auto WRITET = [&](int b) {
        char* dA = lds + b * 24576;
        char* dB = dA + 16384;
#pragma unroll
        for (int t = 0; t < 4; ++t)
            *(u32x4*)(dA + t * 4096 + wave * 1024 + lane * 16) = PACK(rA[t][0], rA[t][1]);
#pragma unroll
        for (int t = 0; t < 2; ++t)
            *(u32x4*)(dB + t * 4096 + wave * 1024 + lane * 16) = PACK(rB[t][0], rB[t][1]);
    };
    auto COMPUTE = [&](int b) {
        char* sA = lds + b * 24576;
        char* sB = sA + 16384;
#pragma unroll
        for (int ks = 0; ks < 2; ++ks) {
            bf16x8 af[4], bfr[2];
#pragma unroll
            for (int mi = 0; mi < 4; ++mi) {
                int m_loc = wr * 64 + mi * 16 + lr;
                int gr = (ks * 4 + lk) ^ (m_loc & 7);
                af[mi] = *(const bf16x8*)(sA + m_loc * 128 + gr * 16);
            }
#pragma unroll
            for (int ni = 0; ni < 2; ++ni) {
                int n_loc = wc * 32 + ni * 16 + lr;
                int gr = (ks * 4 + lk) ^ (n_loc & 7);
                bfr[ni] = *(const bf16x8*)(sB + n_loc * 128 + gr * 16);
            }
#pragma unroll
            for (int mi = 0; mi < 4; ++mi)
#pragma unroll
                for (int ni = 0; ni < 2; ++ni)
                    acc[mi][ni] = __builtin_amdgcn_mfma_f32_16x16x32_bf16(
                        af[mi], bfr[ni], acc[mi][ni], 0, 0, 0);
        }
    };

    LOADT(0);
    WRITET(0);
    __syncthreads();
    int b = 0;
    for (int kt = 0; kt < nk - 1; ++kt) {
        LOADT(kt + 1);     // issue early: latency hides under COMPUTE
        COMPUTE(b);
        WRITET(b ^ 1);     // waits loads, packs, ds_writes
        __syncthreads();
        b ^= 1;
    }
    COMPUTE(b);

#pragma unroll
    for (int mi = 0; mi < 4; ++mi) {
#pragma unroll
        for (int ni = 0; ni < 2; ++ni) {
            const int n_g = nb + wc * 32 + ni * 16 + lr;
            const float bv = bias[n_g];
#pragma unroll
            for (int r = 0; r < 4; ++r) {
                const int m_g = mb + wr * 64 + mi * 16 + lk * 4 + r;
                float v = acc[mi][ni][r] + bv;
                if (RELU) v = fmaxf(v, 0.f);
                if (HASRES) v += res[(size_t)m_g * lda + n_g];
                if (MODE == 2) outH[(size_t)m_g * 768 + n_g] = (_Float16)v;
                else           outB[(size_t)m_g * ldo + n_g] = f2bf(v);
            }
        }
    }
}

// ---------------------------------------------------------------------------
// launch 1: down0 (96 tiles, f32 src) + adapter (192 tiles, f32 src:
// adFH = f16(x@aW.T + ab + x)) + cvt of chain/u3 weights + protos.
// ---------------------------------------------------------------------------
__global__ __launch_bounds__(256, 2) void gemm_d0ad_cvt(
    const float* __restrict__ x, const float* __restrict__ Wd0,
    const float* __restrict__ bd0, u16* __restrict__ h1,
    const float* __restrict__ aW, const float* __restrict__ ab,
    _Float16* __restrict__ adFH, CvtTab tabB)
{
    __shared__ __align__(16) char lds[49152];
    const int bid = blockIdx.x;
    if (bid < 96) {
        gemm128_f32<1, 0, 0>(lds, x, 768, Wd0, 768, bd0, h1, 384,
                             nullptr, nullptr, 12,
                             (bid & 15) * 128, (bid >> 4) * 64);
    } else if (bid < 288) {
        const int b2 = bid - 96;
        gemm128_f32<0, 1, 2>(lds, x, 768, aW, 768, ab, nullptr, 0,
                             x, adFH, 12,
                             (b2 & 15) * 128, (b2 >> 4) * 64);
    } else {
        do_cvt(tabB, bid - 288, threadIdx.x);
    }
}

// ---------------------------------------------------------------------------
// chain512: d1..u2, 128 blocks x 512 thr (8 waves = 4 N-waves x 2 K-waves).
// ---------------------------------------------------------------------------
template<int K, int NPAD, int NREAL, int RES, int OUTG>
__device__ __forceinline__ void layer16s(
    const u16* __restrict__ W, int ldw, const float* __restrict__ bias,
    const u16* actIn, int ldin,
    u16* actOut, int ldout,
    const u16* resid, int ldres,
    u16* __restrict__ gout, int ldg,
    float* comb)
{
    constexpr int TPW = NPAD / 64;
    constexpr int KK = K / 32;
    constexpr int KH = KK / 2;
    const int tid = threadIdx.x;
    const int w = tid >> 6, lane = tid & 63;
    const int nw = w & 3, kw = w >> 2;
    const int lr = lane & 15, lk = lane >> 4;

    f32x4 acc[TPW];
#pragma unroll
    for (int t = 0; t < TPW; ++t)
#pragma unroll
        for (int e = 0; e < 4; ++e) acc[t][e] = 0.f;

#pragma unroll
    for (int s = 0; s < KH; ++s) {
        const int kk = kw * KH + s;
        const bf16x8 a = *(const bf16x8*)&actIn[lr * ldin + kk * 32 + lk * 8];
#pragma unroll
        for (int t = 0; t < TPW; ++t) {
            const int nc = (nw * TPW + t) * 16 + lr;
            const bf16x8 b = *(const bf16x8*)&W[(size_t)nc * ldw + kk * 32 + lk * 8];
            acc[t] = __builtin_amdgcn_mfma_f32_16x16x32_bf16(a, b, acc[t], 0, 0, 0);
        }
    }
    if (kw == 1) {
#pragma unroll
        for (int t = 0; t < TPW; ++t)
            *(f32x4*)(comb + ((size_t)(nw * TPW + t) * 64 + lane) * 4) = acc[t];
    }
    __syncthreads();
    if (kw == 0) {
#pragma unroll
        for (int t = 0; t < TPW; ++t) {
            const f32x4 o = *(const f32x4*)(comb + ((size_t)(nw * TPW + t) * 64 + lane) * 4);
            const int nc = (nw * TPW + t) * 16 + lr;
            const float bv = (nc < NREAL) ? bias[nc] : 0.f;
#pragma unroll
            for (int r = 0; r < 4; ++r) {
                const int row = lk * 4 + r;
                float v = fmaxf(acc[t][r] + o[r] + bv, 0.f);
                if (RES) v += bf2f(resid[row * ldres + nc]);
                const u16 ov = f2bf(v);
                if (OUTG) gout[(size_t)row * ldg + nc] = ov;
                else      actOut[row * ldout + nc] = ov;
            }
        }
    }
    __syncthreads();
}

__global__ __launch_bounds__(512) void chain512(
    const u16* __restrict__ h1,
    const u16* __restrict__ Wd1b, const float* __restrict__ bd1,
    const u16* __restrict__ Wd2b, const float* __restrict__ bd2,
    const u16* __restrict__ Wd3b, const float* __restrict__ bd3,
    const u16* __restrict__ Wu0b, const float* __restrict__ bu0,
    const u16* __restrict__ Wu1b, const float* __restrict__ bu1,
    const u16* __restrict__ Wu2b, const float* __restrict__ bu2,
    u16* __restrict__ u2)
{
    __shared__ u16 As[16 * 392];
    __shared__ u16 Bs[16 * 200];
    __shared__ u16 Cs[16 * 136];
    __shared__ u16 Ds[16 * 72];
    __shared__ float comb[6144];      // 24 tiles x 64 lanes x f32x4 = 24576 B
    const int tid = threadIdx.x;
    const int rb = blockIdx.x * 16;

    for (int i = tid; i < 768; i += 512) {
        const int r = i / 48, c = i - r * 48;
        *(bf16x8*)&As[r * 392 + c * 8] =
            *(const bf16x8*)&h1[(size_t)(rb + r) * 384 + c * 8];
    }
    __syncthreads();
    layer16s<384, 192, 192, 0, 0>(Wd1b, 384, bd1, As, 392, Bs, 200, nullptr, 0, nullptr, 0, comb);
    layer16s<192, 128,  96, 0, 0>(Wd2b, 192, bd2, Bs, 200, Cs, 136, nullptr, 0, nullptr, 0, comb);
    layer16s<128,  64,  48, 0, 0>(Wd3b, 128, bd3, Cs, 136, Ds,  72, nullptr, 0, nullptr, 0, comb);
    u16* E = As;
    u16* F = As + 16 * 136;
    layer16s< 64, 128,  96, 1, 0>(Wu0b,  64, bu0, Ds,  72, E, 136, Cs, 136, nullptr, 0, comb);
    layer16s<128, 192, 192, 1, 0>(Wu1b, 128, bu1, E, 136, F, 200, Bs, 200, nullptr, 0, comb);
    layer16s<192, 384, 384, 0, 1>(Wu2b, 192, bu2, F, 200, nullptr, 0, nullptr, 0,
                                  u2 + (size_t)rb * 384, 384, comb);
}

// launch 3: featH = f16( relu(u2@Wu3.T + bu3) + adFH )
__global__ __launch_bounds__(256, 2) void gemm_u3(
    const u16* __restrict__ u2, const u16* __restrict__ Wu3b,
    const float* __restrict__ bu3, const _Float16* __restrict__ adFH,
    _Float16* __restrict__ featH)
{
    __shared__ __align__(16) char lds[49152];
    gemm128_body<1, 1, 1, 2>(lds, u2, 384, Wu3b, 384, bu3, nullptr, 0,
                             adFH, 768, featH, 6,
                             blockIdx.x * 128, blockIdx.y * 64);
}

// ---------------------------------------------------------------------------
// launch 4: L1 head (proven R13 pair — NO fences/atomics; the R14 fused
// reduction's device-scope threadfences cost ~100us in L2 writebacks).
// part[row][z][p] = -sum_{d in 96-chunk z} |feat - proto|
// Grid (16 rb, 4 pb, 8 z) = 512 blocks. Block: 128 rows x 64 p x 96 d.
// ---------------------------------------------------------------------------
__global__ __launch_bounds__(256) void l1_kernel(
    const _Float16* __restrict__ feat, const _Float16* __restrict__ protos,
    float* __restrict__ part)
{
    __shared__ _Float16 fs[128][96];   // 24576 B
    __shared__ hf2 pt[48][64];         // 12288 B  [d-pair][proto]
    const int tid = threadIdx.x;
    const int tp = tid & 15, tr = tid >> 4;
    const int rb = blockIdx.x * 128;
    const int pb = blockIdx.y * 64;
    const int db = blockIdx.z * 96;

    for (int i = tid; i < 1536; i += 256) {
        const int r = i / 12, c = i - r * 12;
        *(hf8*)&fs[r][c * 8] =
            *(const hf8*)&feat[(size_t)(rb + r) * 768 + db + c * 8];
    }
    {
        const int sp = tid & 63, q = tid >> 6;
#pragma unroll
        for (int t = 0; t < 3; ++t) {
            const hf8 v = *(const hf8*)&protos[(size_t)(pb + sp) * 768 + db + q * 24 + t * 8];
            const hf2x4 w = __builtin_bit_cast(hf2x4, v);
            const int p0 = q * 12 + t * 4;
#pragma unroll
            for (int e = 0; e < 4; ++e)
                pt[p0 + e][sp] = w.v[e];
        }
    }
    __syncthreads();

    float acc[8][4];
#pragma unroll
    for (int i = 0; i < 8; ++i)
#pragma unroll
        for (int j = 0; j < 4; ++j) acc[i][j] = 0.f;

    const hf2 one2 = {(_Float16)1.0f, (_Float16)1.0f};
#pragma unroll 2
    for (int g = 0; g < 12; ++g) {
        hf2x4 F2[8];
#pragma unroll
        for (int i = 0; i < 8; ++i)
            F2[i] = __builtin_bit_cast(hf2x4, *(const hf8*)&fs[tr + 16 * i][g * 8]);
        hf2x4 P2[4];
#pragma unroll
        for (int q = 0; q < 4; ++q)
            P2[q] = __builtin_bit_cast(hf2x4, *(const hf8*)&pt[g * 4 + q][tp * 4]);
#pragma unroll
        for (int q = 0; q < 4; ++q) {
#pragma unroll
            for (int j = 0; j < 4; ++j) {
                const hf2 pj = P2[q].v[j];
#pragma unroll
                for (int i = 0; i < 8; ++i) {
                    hf2 d = F2[i].v[q] - pj;
                    unsigned ud = __builtin_bit_cast(unsigned, d) & 0x7FFF7FFFu;
                    acc[i][j] = FDOT2(__builtin_bit_cast(hf2, ud), one2, acc[i][j]);
                }
            }
        }
    }
    const int p = pb + tp * 4;
    if (p < 200) {
#pragma unroll
        for (int i = 0; i < 8; ++i) {
            float4 v = {-acc[i][0], -acc[i][1], -acc[i][2], -acc[i][3]};
            *(float4*)&part[((size_t)(rb + tr + 16 * i) * 8 + blockIdx.z) * 200 + p] = v;
        }
    }
}

// out[row][p] = sum_z part[row][z][p]; one block per row (6.4KB contiguous)
__global__ __launch_bounds__(256) void l1_reduce(
    const float* __restrict__ part, float* __restrict__ out)
{
    const int row = blockIdx.x;
    const int p = threadIdx.x;
    if (p < 200) {
        float s = 0.f;
#pragma unroll
        for (int z = 0; z < 8; ++z)
            s += part[((size_t)row * 8 + z) * 200 + p];
        out[(size_t)row * 200 + p] = s;
    }
}

// ---------------------------------------------------------------------------
// Workspace layout (bytes). PART (13.1 MB) aliases chain/u3 weights (dead by
// the time l1 runs). featH/proH live above. x/aW/Wd0 read as f32 inputs.
// ---------------------------------------------------------------------------
static constexpr size_t OFF_PART  = 0;          // 2048 x 8 x 200 f32 partials
static constexpr size_t OFF_WD1   = 4915200;
static constexpr size_t OFF_WD2   = 5062656;
static constexpr size_t OFF_WD3   = 5111808;
static constexpr size_t OFF_WU0   = 5128192;
static constexpr size_t OFF_WU1   = 5144576;
static constexpr size_t OFF_WU2   = 5193728;
static constexpr size_t OFF_WU3   = 5341184;
static constexpr size_t OFF_H1    = 5931008;    // 2048x384 bf16
static constexpr size_t OFF_U2    = 10387456;   // 2048x384 bf16
static constexpr size_t OFF_ADF   = 11960320;   // 2048x768 f16 (dead pre-l1)
static constexpr size_t OFF_FEATH = 19660800;   // 2048x768 f16
static constexpr size_t OFF_PROH  = 22806528;   // 256x768 f16

extern "C" void kernel_launch(void* const* d_in, const int* in_sizes, int n_in,
                              void* d_out, int out_size, void* d_ws, size_t ws_size,
                              hipStream_t stream) {
    const float* x      = (const float*)d_in[0];
    const float* aW     = (const float*)d_in[1];
    const float* ab     = (const float*)d_in[2];
    const float* protos = (const float*)d_in[3];
    const float* Wd[4]  = {(const float*)d_in[4], (const float*)d_in[6],
                           (const float*)d_in[8], (const float*)d_in[10]};
    const float* bd[4]  = {(const float*)d_in[5], (const float*)d_in[7],
                           (const float*)d_in[9], (const float*)d_in[11]};
    const float* Wu[4]  = {(const float*)d_in[12], (const float*)d_in[14],
                           (const float*)d_in[16], (const float*)d_in[18]};
    const float* bu[4]  = {(const float*)d_in[13], (const float*)d_in[15],
                           (const float*)d_in[17], (const float*)d_in[19]};
    float* out = (float*)d_out;
    char* ws = (char*)d_ws;

    u16* Wd1b  = (u16*)(ws + OFF_WD1);
    u16* Wd2b  = (u16*)(ws + OFF_WD2);
    u16* Wd3b  = (u16*)(ws + OFF_WD3);
    u16* Wu0b  = (u16*)(ws + OFF_WU0);
    u16* Wu1b  = (u16*)(ws + OFF_WU1);
    u16* Wu2b  = (u16*)(ws + OFF_WU2);
    u16* Wu3b  = (u16*)(ws + OFF_WU3);
    u16* h1    = (u16*)(ws + OFF_H1);
    u16* u2    = (u16*)(ws + OFF_U2);
    float* part = (float*)(ws + OFF_PART);
    _Float16* adFH  = (_Float16*)(ws + OFF_ADF);
    _Float16* featH = (_Float16*)(ws + OFF_FEATH);
    _Float16* proH  = (_Float16*)(ws + OFF_PROH);

    const int SENT = 0x7FFFFFFF;

    // --- launch 1: down0 + adapter (f32 sources) + cvt of chain/u3/proto ---
    CvtTab tabB;
    int blkB = 0;
    auto setB = [&](int i, const float* s, u16* d, int N, int K, int Np, int Kp,
                    int fmt) {
        tabB.t[i] = {s, d, N, K, Np, Kp, blkB, fmt};
        blkB += (Np * Kp + 255) / 256;
    };
    setB(0, Wd[1],  Wd1b,       192, 384, 192, 384, 0);
    setB(1, Wd[2],  Wd2b,       96,  192, 128, 192, 0);
    setB(2, Wd[3],  Wd3b,       48,  96,  64,  128, 0);
    setB(3, Wu[0],  Wu0b,       96,  48,  128, 64,  0);
    setB(4, Wu[1],  Wu1b,       192, 96,  192, 128, 0);
    setB(5, Wu[2],  Wu2b,       384, 192, 384, 192, 0);
    setB(6, Wu[3],  Wu3b,       768, 384, 768, 384, 0);
    setB(7, protos, (u16*)proH, 200, 768, 256, 768, 1);
    for (int j = 8; j < 11; ++j) tabB.t[j].blk0 = SENT;
    gemm_d0ad_cvt<<<288 + blkB, 256, 0, stream>>>(x, Wd[0], bd[0], h1,
                                                  aW, ab, adFH, tabB);

    // --- launch 2: chain d1..u2 ---
    chain512<<<128, 512, 0, stream>>>(h1,
        Wd1b, bd[1], Wd2b, bd[2], Wd3b, bd[3],
        Wu0b, bu[0], Wu1b, bu[1], Wu2b, bu[2], u2);

    // --- launch 3: featH = relu(u2@Wu3.T + bu3) + adFH ---
    gemm_u3<<<dim3(16, 12), 256, 0, stream>>>(u2, Wu3b, bu[3], adFH, featH);

    // --- launch 4+5: L1 head partials (z=8), then reduce ---
    l1_kernel<<<dim3(16, 4, 8), 256, 0, stream>>>(featH, proH, part);
    l1_reduce<<<dim3(2048), 256, 0, stream>>>(part, out);
}